// Round 2
// baseline (294.558 us; speedup 1.0000x reference)
//
#include <hip/hip_runtime.h>
#include <hip/hip_bf16.h>
#include <stdint.h>

// ---------------------------------------------------------------------------
// wannModel: x0 = x@Ws^T + bs;  h_{l+1} = relu(h_l@W_l^T + b_l) + x0 (32x);
//            out = softmax(h@Wo^T + bo)  over 64 classes.
//
// Strategy: transposed-orientation MFMA chain (out^T = W * h^T) so that the
// MFMA C/D layout (col = lane&15 = batch) is lane-compatible with the next
// layer's B-operand layout (lane&15 = batch col). The k-index mismatch between
// C rows (4q+r+16nt) and B slots (8q+j+32kt) is absorbed by pre-permuting the
// weights' k axis with pi(8q+j+32kt) = 4q+(j&3)+16*(j>>2)+32kt in a tiny
// preprocessing kernel that also converts to bf16 and lays frags out linearly
// (perfect for global_load_lds width-16 staging and conflict-free ds_read_b128).
// h never touches LDS: it stays in registers across all 32 layers.
//
// R1 fix: W_out frags are read straight from global in the epilogue (16 KB,
// L2-resident) instead of a half-staged out-of-bounds LDS region (NaN source).
// LDS = 64 KB exactly (two 32 KB weight double-buffers).
// ---------------------------------------------------------------------------

typedef short bs8 __attribute__((ext_vector_type(8)));   // 8 x bf16 bits (4 VGPR)
typedef float f32x4 __attribute__((ext_vector_type(4)));

union Frag {
  bs8 v;
  uint32_t u[4];
};

__device__ __forceinline__ uint16_t f2bf_rne(float f) {
  union { float f; uint32_t u; } c; c.f = f;
  uint32_t r = c.u + 0x7fffu + ((c.u >> 16) & 1u);   // round-to-nearest-even
  return (uint16_t)(r >> 16);
}

__device__ __forceinline__ uint32_t pack2bf(float lo, float hi) {
  float2 t; t.x = lo; t.y = hi;
  __hip_bfloat162 b = __float22bfloat162_rn(t);      // RNE pair convert
  union { __hip_bfloat162 b; uint32_t u; } c; c.b = b;
  return c.u;                                        // low 16 = lo
}

// ---------------------------------------------------------------------------
// Preprocess: build bf16 weight fragments in d_ws.
// Layout (uint16 elements):
//   [0,16384)         W_start frags, NATURAL k order (x is loaded naturally)
//   [16384,540672)    32 chain-layer frags, PI-permuted k
//   [540672,548864)   W_out frags, PI-permuted k
// Frag element offset within region: ((nt*4+kt)*64 + lane)*8 + j
// ---------------------------------------------------------------------------
__global__ void prep_frags(const float* __restrict__ w_start,
                           const float* __restrict__ masked_w,
                           const float* __restrict__ w_out,
                           uint16_t* __restrict__ dst) {
  int e = blockIdx.x * 256 + threadIdx.x;
  if (e >= 548864) return;
  int j    = e & 7;
  int lane = (e >> 3) & 63;
  int kt   = (e >> 9) & 3;       // region bases are multiples of 2048, so ok
  int q    = lane >> 4;
  int m15  = lane & 15;
  float val;
  if (e < 16384) {
    int nt = (e >> 11) & 7;
    int n = nt * 16 + m15;
    int k = q * 8 + j + kt * 32;                       // natural
    val = w_start[n * 128 + k];
  } else if (e < 540672) {
    int e2 = e - 16384;
    int l  = e2 >> 14;
    int nt = (e2 >> 11) & 7;
    int n = nt * 16 + m15;
    int k = q * 4 + (j & 3) + 16 * (j >> 2) + kt * 32; // pi-permuted
    val = masked_w[(l * 128 + n) * 128 + k];
  } else {
    int e2 = e - 540672;
    int nt = (e2 >> 11) & 3;
    int n = nt * 16 + m15;
    int k = q * 4 + (j & 3) + 16 * (j >> 2) + kt * 32; // pi-permuted
    val = w_out[n * 128 + k];
  }
  dst[e] = f2bf_rne(val);
}

// ---------------------------------------------------------------------------
// Main kernel. Block = 256 threads = 4 waves; each wave owns 64 batch columns
// (4 m-tiles of 16). Grid 512 blocks = exactly 2 resident blocks per CU.
// LDS (dynamic, 65536 B): bufA[32KB] | bufB[32KB]  (weight double-buffer).
// Per layer: one barrier, stage next layer's 32KB via global_load_lds(16B),
// 4 N-quarter passes x (8 ds_read_b128 + 32 MFMA + relu/residual/repack).
// ---------------------------------------------------------------------------
extern __shared__ uint16_t lds[];

__global__ void __launch_bounds__(256, 2)
wann_main(const float* __restrict__ x,
          const float* __restrict__ b_start,
          const float* __restrict__ layer_b,
          const float* __restrict__ b_out,
          const uint16_t* __restrict__ wfrag,
          float* __restrict__ out) {
  const int tid  = threadIdx.x;
  const int lane = tid & 63;
  const int wave = tid >> 6;
  const int q    = lane >> 4;
  const int mc   = lane & 15;
  const long batch0 = (long)blockIdx.x * 256 + wave * 64;

  uint16_t* bufA = lds;
  uint16_t* bufB = lds + 16384;

  auto stage_buf = [&](uint16_t* dstb, const uint16_t* srcb) {
    #pragma unroll
    for (int i = 0; i < 8; ++i) {
      __builtin_amdgcn_global_load_lds(
          (const __attribute__((address_space(1))) void*)(srcb + i * 2048 + wave * 512 + lane * 8),
          (__attribute__((address_space(3))) void*)(dstb + i * 2048 + wave * 512),
          16, 0, 0);
    }
  };

  // ---- stage W_start (bufA) ----
  stage_buf(bufA, wfrag);

  // ---- load x fragments (natural k order: B[k=8q+j+32kt][batch=mc]) ----
  Frag xf[4][4];
  #pragma unroll
  for (int mt = 0; mt < 4; ++mt) {
    const float* xrow = x + (batch0 + mt * 16 + mc) * 128 + q * 8;
    #pragma unroll
    for (int kt = 0; kt < 4; ++kt) {
      float4 a = *reinterpret_cast<const float4*>(xrow + kt * 32);
      float4 b = *reinterpret_cast<const float4*>(xrow + kt * 32 + 4);
      xf[mt][kt].u[0] = pack2bf(a.x, a.y);
      xf[mt][kt].u[1] = pack2bf(a.z, a.w);
      xf[mt][kt].u[2] = pack2bf(b.x, b.y);
      xf[mt][kt].u[3] = pack2bf(b.z, b.w);
    }
  }

  __syncthreads();                 // W_start staged (vmcnt drained at barrier)
  stage_buf(bufB, wfrag + 16384);  // stage layer 0 during start matmul

  // ---- start layer: x0^T = Ws * x^T + bs (no relu, no residual) ----
  Frag x0f[4][4];   // [mt][kt']  bf16 B-frags of x0 (pi-convention)
  Frag hfr[4][4];   // [mt][kt']  bf16 B-frags of h  (pi-convention)
  #pragma unroll
  for (int p = 0; p < 4; ++p) {
    f32x4 acc[2][4];
    #pragma unroll
    for (int ntl = 0; ntl < 2; ++ntl) {
      const int nt = 2 * p + ntl;
      const float4 bb = *reinterpret_cast<const float4*>(b_start + nt * 16 + q * 4);
      #pragma unroll
      for (int mt = 0; mt < 4; ++mt) {
        acc[ntl][mt][0] = bb.x; acc[ntl][mt][1] = bb.y;
        acc[ntl][mt][2] = bb.z; acc[ntl][mt][3] = bb.w;
      }
    }
    #pragma unroll
    for (int kt = 0; kt < 4; ++kt) {
      #pragma unroll
      for (int ntl = 0; ntl < 2; ++ntl) {
        const int nt = 2 * p + ntl;
        Frag wf;
        wf.v = *reinterpret_cast<const bs8*>(bufA + ((nt * 4 + kt) * 64 + lane) * 8);
        #pragma unroll
        for (int mt = 0; mt < 4; ++mt)
          acc[ntl][mt] = __builtin_amdgcn_mfma_f32_16x16x32_bf16(wf.v, xf[mt][kt].v, acc[ntl][mt], 0, 0, 0);
      }
    }
    #pragma unroll
    for (int mt = 0; mt < 4; ++mt) {
      #pragma unroll
      for (int ntl = 0; ntl < 2; ++ntl) {   // pass p emits frag kt'=p, slots j'=4*ntl+r
        x0f[mt][p].u[2 * ntl + 0] = pack2bf(acc[ntl][mt][0], acc[ntl][mt][1]);
        x0f[mt][p].u[2 * ntl + 1] = pack2bf(acc[ntl][mt][2], acc[ntl][mt][3]);
      }
    }
  }
  #pragma unroll
  for (int mt = 0; mt < 4; ++mt)
    #pragma unroll
    for (int kt = 0; kt < 4; ++kt)
      hfr[mt][kt].v = x0f[mt][kt].v;        // h = x0

  // ---- 32-layer chain; layer l weights live in buf[(l+1)&1] ----
  const uint16_t* chain = wfrag + 16384;
  for (int l = 0; l < 32; ++l) {
    __syncthreads();  // staging of layer l complete; layer l-1 reads retired
    uint16_t* wl  = (l & 1) ? bufA : bufB;
    uint16_t* nxt = (l & 1) ? bufB : bufA;
    if (l < 31) stage_buf(nxt, chain + (l + 1) * 16384);
    const float* bl = layer_b + l * 128;

    uint32_t tq[3][4][4];  // new-h frags for passes 0..2 (h_old still needed)
    #pragma unroll
    for (int p = 0; p < 4; ++p) {
      f32x4 acc[2][4];
      #pragma unroll
      for (int ntl = 0; ntl < 2; ++ntl) {
        const int nt = 2 * p + ntl;
        const float4 bb = *reinterpret_cast<const float4*>(bl + nt * 16 + q * 4);
        #pragma unroll
        for (int mt = 0; mt < 4; ++mt) {
          acc[ntl][mt][0] = bb.x; acc[ntl][mt][1] = bb.y;
          acc[ntl][mt][2] = bb.z; acc[ntl][mt][3] = bb.w;
        }
      }
      #pragma unroll
      for (int kt = 0; kt < 4; ++kt) {
        #pragma unroll
        for (int ntl = 0; ntl < 2; ++ntl) {
          const int nt = 2 * p + ntl;
          Frag wf;
          wf.v = *reinterpret_cast<const bs8*>(wl + ((nt * 4 + kt) * 64 + lane) * 8);
          #pragma unroll
          for (int mt = 0; mt < 4; ++mt)
            acc[ntl][mt] = __builtin_amdgcn_mfma_f32_16x16x32_bf16(wf.v, hfr[mt][kt].v, acc[ntl][mt], 0, 0, 0);
        }
      }
      // relu + residual(x0 bf16 unpack) + bf16 repack into next-layer B-frags
      #pragma unroll
      for (int mt = 0; mt < 4; ++mt) {
        #pragma unroll
        for (int ntl = 0; ntl < 2; ++ntl) {
          uint32_t xw0 = x0f[mt][p].u[2 * ntl + 0];
          uint32_t xw1 = x0f[mt][p].u[2 * ntl + 1];
          float v0 = fmaxf(acc[ntl][mt][0], 0.0f) + __uint_as_float(xw0 << 16);
          float v1 = fmaxf(acc[ntl][mt][1], 0.0f) + __uint_as_float(xw0 & 0xffff0000u);
          float v2 = fmaxf(acc[ntl][mt][2], 0.0f) + __uint_as_float(xw1 << 16);
          float v3 = fmaxf(acc[ntl][mt][3], 0.0f) + __uint_as_float(xw1 & 0xffff0000u);
          uint32_t pw0 = pack2bf(v0, v1);
          uint32_t pw1 = pack2bf(v2, v3);
          if (p < 3) {
            tq[p][mt][2 * ntl + 0] = pw0;
            tq[p][mt][2 * ntl + 1] = pw1;
          } else {        // pass 3: h_old[kt=3] dead after this pass's MFMAs
            hfr[mt][3].u[2 * ntl + 0] = pw0;
            hfr[mt][3].u[2 * ntl + 1] = pw1;
          }
        }
      }
    }
    #pragma unroll
    for (int mt = 0; mt < 4; ++mt)
      #pragma unroll
      for (int p = 0; p < 3; ++p)
        #pragma unroll
        for (int w = 0; w < 4; ++w)
          hfr[mt][p].u[w] = tq[p][mt][w];
  }

  // ---- output layer: logits^T = Wo * h^T + bo  (n = 0..63) ----
  // W_out frags read directly from global (16 KB, L2/L3-resident, coalesced).
  const uint16_t* wout = wfrag + 540672;
  f32x4 ao[4][4];  // [nt][mt]
  #pragma unroll
  for (int nt = 0; nt < 4; ++nt) {
    const float4 bb = *reinterpret_cast<const float4*>(b_out + nt * 16 + q * 4);
    #pragma unroll
    for (int mt = 0; mt < 4; ++mt) {
      ao[nt][mt][0] = bb.x; ao[nt][mt][1] = bb.y;
      ao[nt][mt][2] = bb.z; ao[nt][mt][3] = bb.w;
    }
  }
  #pragma unroll
  for (int kt = 0; kt < 4; ++kt) {
    #pragma unroll
    for (int nt = 0; nt < 4; ++nt) {
      Frag wf;
      wf.v = *reinterpret_cast<const bs8*>(wout + ((nt * 4 + kt) * 64 + lane) * 8);
      #pragma unroll
      for (int mt = 0; mt < 4; ++mt)
        ao[nt][mt] = __builtin_amdgcn_mfma_f32_16x16x32_bf16(wf.v, hfr[mt][kt].v, ao[nt][mt], 0, 0, 0);
    }
  }

  // ---- softmax over 64 classes (4 lanes x 16 vals per batch col) + store ----
  // Transpose scratch: bufB region is free for THIS wave after the last
  // barrier (layer 31 reads bufA only). Per-wave 16x68 floats (4352 B).
  float* tr = reinterpret_cast<float*>(lds + 16384) + wave * 1088;
  #pragma unroll
  for (int mt = 0; mt < 4; ++mt) {
    float e[16];
    float M = -3.0e38f;
    #pragma unroll
    for (int nt = 0; nt < 4; ++nt)
      #pragma unroll
      for (int r = 0; r < 4; ++r)
        M = fmaxf(M, ao[nt][mt][r]);
    M = fmaxf(M, __shfl_xor(M, 16, 64));
    M = fmaxf(M, __shfl_xor(M, 32, 64));
    float S = 0.0f;
    #pragma unroll
    for (int nt = 0; nt < 4; ++nt)
      #pragma unroll
      for (int r = 0; r < 4; ++r) {
        float t = exp2f((ao[nt][mt][r] - M) * 1.4426950408889634f);
        e[nt * 4 + r] = t;
        S += t;
      }
    S += __shfl_xor(S, 16, 64);
    S += __shfl_xor(S, 32, 64);
    const float inv = 1.0f / S;
    #pragma unroll
    for (int nt = 0; nt < 4; ++nt) {
      float4 pv;
      pv.x = e[nt * 4 + 0] * inv;
      pv.y = e[nt * 4 + 1] * inv;
      pv.z = e[nt * 4 + 2] * inv;
      pv.w = e[nt * 4 + 3] * inv;
      *reinterpret_cast<float4*>(tr + mc * 68 + nt * 16 + q * 4) = pv;
    }
    __asm__ volatile("s_waitcnt lgkmcnt(0)" ::: "memory");
    #pragma unroll
    for (int it = 0; it < 4; ++it) {
      int row = it * 4 + (lane >> 4);
      float4 v = *reinterpret_cast<const float4*>(tr + row * 68 + (lane & 15) * 4);
      long gr = batch0 + mt * 16 + row;
      *reinterpret_cast<float4*>(out + gr * 64 + (lane & 15) * 4) = v;
    }
    __asm__ volatile("s_waitcnt lgkmcnt(0)" ::: "memory");
  }
}

// ---------------------------------------------------------------------------
extern "C" void kernel_launch(void* const* d_in, const int* in_sizes, int n_in,
                              void* d_out, int out_size, void* d_ws, size_t ws_size,
                              hipStream_t stream) {
  const float* x        = (const float*)d_in[0];
  const float* w_start  = (const float*)d_in[1];
  const float* b_start  = (const float*)d_in[2];
  const float* masked_w = (const float*)d_in[3];
  const float* layer_b  = (const float*)d_in[4];
  const float* w_out    = (const float*)d_in[5];
  const float* b_out    = (const float*)d_in[6];
  uint16_t* wfrag = (uint16_t*)d_ws;   // needs 1,097,728 B < ws_size

  prep_frags<<<2144, 256, 0, stream>>>(w_start, masked_w, w_out, wfrag);
  wann_main<<<512, 256, 65536, stream>>>(x, b_start, layer_b, b_out, wfrag,
                                         (float*)d_out);
}